// Round 1
// 240.975 us; speedup vs baseline: 1.0545x; 1.0545x over previous
//
#include <hip/hip_runtime.h>

#define N_NODES 100000
#define N_EDGES 1600000
#define F 128
#define NB_C 196            // coarse buckets = ceil(N_NODES/512)
#define CHUNK 4000
#define NBLK_BIN 400        // 400 * 4000 = 1.6M exact
#define CAP 9984            // finesort LDS capacity (mean 8163, +20 sigma)
#define NGROUP 6250         // N_NODES / 16

// ---------------- workspace layout (bytes) ----------------
// pool   : N_EDGES ints    @ 0        (6,400,000)
// (gap)  : former offs     @ 6400000  (unused, layout kept)
// base_t : 196*400 ints    @ 6801408  (313,600)   bucket-major count matrix
// btot   : 256 ints        @ 7115008  (1,024)
// (gap)  : former bbase    @ 7116032  (unused)
// h      : N*128 bf16      @ 7117056  (25,600,000)
// total 32,717,056 (< 32,804,864 proven available)
#define WS_V6 32717056

typedef __attribute__((ext_vector_type(8))) short short8;
typedef __attribute__((ext_vector_type(4))) float f32x4;

__device__ __forceinline__ unsigned short f2bf(float f) {
    unsigned u = __float_as_uint(f);
    return (unsigned short)((u + 0x7fffu + ((u >> 16) & 1u)) >> 16);
}

// ---------------------------------------------------------------------------
// prep + chist fused: all blocks do h[i][j] = bf16(feat[i][j]/out_norm[i]);
// blocks 0..399 additionally histogram their 4000-edge chunk into 196 coarse
// buckets (dst>>9), bucket-major output base_t[bucket*400 + blk].
// ---------------------------------------------------------------------------
__global__ __launch_bounds__(256) void prep_chist_kernel(
    const float* __restrict__ feat, const float* __restrict__ out_norm,
    const int* __restrict__ dst,
    unsigned short* __restrict__ h, int* __restrict__ base_t)
{
    __shared__ int c[NB_C];
    const int t = threadIdx.x;
    const bool do_hist = (blockIdx.x < NBLK_BIN);
    if (do_hist) {
        if (t < NB_C) c[t] = 0;
        __syncthreads();
    }
    int q = blockIdx.x * 256 + t;      // grid exact: N*32/256
    int row = q >> 5;
    float r = 1.0f / out_norm[row];
    float4 v = ((const float4*)feat)[q];
    ushort4 o;
    o.x = f2bf(v.x * r); o.y = f2bf(v.y * r);
    o.z = f2bf(v.z * r); o.w = f2bf(v.w * r);
    ((ushort4*)h)[q] = o;
    if (do_hist) {
        int e0 = blockIdx.x * CHUNK;
        for (int i = t; i < CHUNK; i += 256)
            atomicAdd(&c[dst[e0 + i] >> 9], 1);
        __syncthreads();
        if (t < NB_C) base_t[t * NBLK_BIN + blockIdx.x] = c[t];
    }
}

// ---------------------------------------------------------------------------
// Phase 2: per-bucket exclusive scan over its 400 per-block counts.
// One wave per bucket, shuffle prefix over contiguous ints. Emits bucket total.
// ---------------------------------------------------------------------------
__global__ __launch_bounds__(64) void cscan1_kernel(
    int* __restrict__ base_t, int* __restrict__ btot)
{
    int b = blockIdx.x, l = threadIdx.x;
    int carry = 0;
    #pragma unroll
    for (int r = 0; r < 7; ++r) {            // 7*64 = 448 >= 400
        int idx = r * 64 + l;
        bool ok = idx < NBLK_BIN;
        int v = ok ? base_t[b * NBLK_BIN + idx] : 0;
        int incl = v;
        #pragma unroll
        for (int off = 1; off < 64; off <<= 1) {
            int n = __shfl_up(incl, off);
            if (l >= off) incl += n;
        }
        if (ok) base_t[b * NBLK_BIN + idx] = incl - v + carry;
        carry += __shfl(incl, 63);
    }
    if (l == 0) btot[b] = carry;
}

// ---------------------------------------------------------------------------
// Phase 3: scatter packed edges ((dst&511)<<17 | src) bucket-grouped.
// Bucket bases recomputed per block from btot (196-entry LDS ladder scan),
// replacing the former single-block cscan2 kernel.
// ---------------------------------------------------------------------------
__global__ __launch_bounds__(256) void binscatter_kernel(
    const int* __restrict__ src, const int* __restrict__ dst,
    const int* __restrict__ base_t, const int* __restrict__ btot,
    int* __restrict__ pool)
{
    __shared__ int cba[NB_C];
    __shared__ int sm[256];
    int t = threadIdx.x, blk = blockIdx.x;
    int v = (t < NB_C) ? btot[t] : 0;
    sm[t] = v;
    __syncthreads();
    for (int off = 1; off < 256; off <<= 1) {
        int x = (t >= off) ? sm[t - off] : 0;
        __syncthreads();
        sm[t] += x;
        __syncthreads();
    }
    if (t < NB_C) cba[t] = (sm[t] - v) + base_t[t * NBLK_BIN + blk];
    __syncthreads();
    int e0 = blk * CHUNK;
    for (int i = t; i < CHUNK; i += 256) {
        int d = dst[e0 + i];
        int s = src[e0 + i];
        int b = d >> 9;
        int pos = atomicAdd(&cba[b], 1);
        pool[pos] = ((d & 511) << 17) | s;
    }
}

// ---------------------------------------------------------------------------
// Phase 4 (fused finesort + gather): per-bucket counting sort entirely in
// LDS (pairs -> sorted src lists, no global write-back), then each wave
// gathers h rows for 32 of the bucket's 512 nodes straight from the LDS
// lists and writes agg (1/in_norm folded). 86 KB LDS -> 1 block/CU,
// 16 waves; 8-deep load unroll keeps in-flight bytes >= the old 72%-occ
// standalone gather.
// ---------------------------------------------------------------------------
__global__ __launch_bounds__(1024) void fsort_gather_kernel(
    const int* __restrict__ pool, const int* __restrict__ btot,
    const unsigned short* __restrict__ h, const float* __restrict__ in_norm,
    float* __restrict__ agg)
{
    __shared__ int pairs[CAP];
    __shared__ int sorted_s[CAP];
    __shared__ int fcnt[512];
    __shared__ int s0[512];
    __shared__ int sexcl[512];
    __shared__ int wsum[8];
    __shared__ int woff[8];
    __shared__ int sbeg[1];

    const int t = threadIdx.x, b = blockIdx.x;
    const int lane = t & 63, wv = t >> 6;

    // beg = sum_{j<b} btot[j]  (wave 0 only, shuffle reduce)
    if (t < 64) {
        int acc = 0;
        for (int j = t; j < NB_C; j += 64) acc += (j < b) ? btot[j] : 0;
        #pragma unroll
        for (int off = 32; off; off >>= 1) acc += __shfl_xor(acc, off);
        if (t == 0) sbeg[0] = acc;
    }
    if (t < 512) fcnt[t] = 0;
    __syncthreads();
    const int beg = sbeg[0];
    int cnt = btot[b];
    if (cnt > CAP) cnt = CAP;   // statistically unreachable

    for (int i = t; i < cnt; i += 1024) pairs[i] = pool[beg + i];
    __syncthreads();
    for (int i = t; i < cnt; i += 1024) atomicAdd(&fcnt[pairs[i] >> 17], 1);
    __syncthreads();

    // inclusive scan of fcnt[512]: per-wave shuffle scan + 8-wide fixup
    if (t < 512) {
        int v = fcnt[t];
        int incl = v;
        #pragma unroll
        for (int off = 1; off < 64; off <<= 1) {
            int n = __shfl_up(incl, off);
            if (lane >= off) incl += n;
        }
        s0[t] = incl;
        if (lane == 63) wsum[wv] = incl;
    }
    __syncthreads();
    if (t < 64) {
        int v = (t < 8) ? wsum[t] : 0;
        int incl = v;
        #pragma unroll
        for (int off = 1; off < 8; off <<= 1) {
            int n = __shfl_up(incl, off);
            if (lane >= off) incl += n;
        }
        if (t < 8) woff[t] = incl - v;
    }
    __syncthreads();
    if (t < 512) {
        int sv = s0[t] + woff[t >> 6];
        s0[t] = sv;                 // local inclusive END per node
        sexcl[t] = sv - fcnt[t];    // local scatter cursor
    }
    __syncthreads();

    // counting-sort scatter into LDS
    for (int i = t; i < cnt; i += 1024) {
        int p = pairs[i];
        int pos = atomicAdd(&sexcl[p >> 17], 1);
        sorted_s[pos] = p & 0x1FFFF;
    }
    __syncthreads();

    // gather: wave wv owns local nodes [wv*32, wv*32+32)
    const unsigned* hp = (const unsigned*)h;
    const int node0 = b << 9;
    const int nEnd = wv * 32 + 32;
    for (int nl = wv * 32; nl < nEnd; ++nl) {
        const int node = node0 + nl;
        if (node >= N_NODES) break;
        const int start = (nl == 0) ? 0 : s0[nl - 1];
        const int end = s0[nl];
        float ax = 0.f, ay = 0.f;
        int e = start;
        for (; e + 7 < end; e += 8) {
            unsigned u0 = hp[(size_t)sorted_s[e]     * 64 + lane];
            unsigned u1 = hp[(size_t)sorted_s[e + 1] * 64 + lane];
            unsigned u2 = hp[(size_t)sorted_s[e + 2] * 64 + lane];
            unsigned u3 = hp[(size_t)sorted_s[e + 3] * 64 + lane];
            unsigned u4 = hp[(size_t)sorted_s[e + 4] * 64 + lane];
            unsigned u5 = hp[(size_t)sorted_s[e + 5] * 64 + lane];
            unsigned u6 = hp[(size_t)sorted_s[e + 6] * 64 + lane];
            unsigned u7 = hp[(size_t)sorted_s[e + 7] * 64 + lane];
            ax += __uint_as_float(u0 << 16) + __uint_as_float(u1 << 16)
                + __uint_as_float(u2 << 16) + __uint_as_float(u3 << 16)
                + __uint_as_float(u4 << 16) + __uint_as_float(u5 << 16)
                + __uint_as_float(u6 << 16) + __uint_as_float(u7 << 16);
            ay += __uint_as_float(u0 & 0xffff0000u) + __uint_as_float(u1 & 0xffff0000u)
                + __uint_as_float(u2 & 0xffff0000u) + __uint_as_float(u3 & 0xffff0000u)
                + __uint_as_float(u4 & 0xffff0000u) + __uint_as_float(u5 & 0xffff0000u)
                + __uint_as_float(u6 & 0xffff0000u) + __uint_as_float(u7 & 0xffff0000u);
        }
        for (; e + 3 < end; e += 4) {
            unsigned u0 = hp[(size_t)sorted_s[e]     * 64 + lane];
            unsigned u1 = hp[(size_t)sorted_s[e + 1] * 64 + lane];
            unsigned u2 = hp[(size_t)sorted_s[e + 2] * 64 + lane];
            unsigned u3 = hp[(size_t)sorted_s[e + 3] * 64 + lane];
            ax += __uint_as_float(u0 << 16) + __uint_as_float(u1 << 16)
                + __uint_as_float(u2 << 16) + __uint_as_float(u3 << 16);
            ay += __uint_as_float(u0 & 0xffff0000u) + __uint_as_float(u1 & 0xffff0000u)
                + __uint_as_float(u2 & 0xffff0000u) + __uint_as_float(u3 & 0xffff0000u);
        }
        for (; e < end; ++e) {
            unsigned u = hp[(size_t)sorted_s[e] * 64 + lane];
            ax += __uint_as_float(u << 16);
            ay += __uint_as_float(u & 0xffff0000u);
        }
        const float rin = 1.0f / in_norm[node];
        float2 o; o.x = ax * rin; o.y = ay * rin;
        ((float2*)agg)[(size_t)node * 64 + lane] = o;
    }
}

// ---------------------------------------------------------------------------
// MFMA transform (in-place on d_out, R3/R4-proven): out = agg @ W^T + b.
// rin already applied by gather. 32 KB LDS, chunk-XOR swizzle.
// ---------------------------------------------------------------------------
__global__ __launch_bounds__(256) void transform_mfma_kernel(
    float* __restrict__ out, const float* __restrict__ W,
    const float* __restrict__ bias)
{
    __shared__ short Wb[F * F];   // 32 KB bf16, chunk-XOR swizzled
    const int t = threadIdx.x;
    #pragma unroll
    for (int i = 0; i < 8; ++i) {
        int c = t + i * 256;
        int n = c >> 4, kc = c & 15;
        const float4* wp = (const float4*)(W + n * F + kc * 8);
        float4 w0 = wp[0], w1 = wp[1];
        short8 v;
        v[0] = (short)f2bf(w0.x); v[1] = (short)f2bf(w0.y);
        v[2] = (short)f2bf(w0.z); v[3] = (short)f2bf(w0.w);
        v[4] = (short)f2bf(w1.x); v[5] = (short)f2bf(w1.y);
        v[6] = (short)f2bf(w1.z); v[7] = (short)f2bf(w1.w);
        *(short8*)&Wb[n * F + ((kc ^ (n & 15)) * 8)] = v;
    }
    __syncthreads();

    const int wave = t >> 6, lane = t & 63;
    const int wblk = blockIdx.x * 4 + wave;
    if (wblk >= NGROUP) return;
    const int r0 = wblk * 16;
    const int m = lane & 15, q = lane >> 4;
    const float4* arow = (const float4*)(out + (size_t)(r0 + m) * F);

    short8 afrag[4];
    #pragma unroll
    for (int s = 0; s < 4; ++s) {
        int k0 = s * 32 + q * 8;
        float4 x0 = arow[k0 >> 2];
        float4 x1 = arow[(k0 >> 2) + 1];
        short8 a;
        a[0] = (short)f2bf(x0.x); a[1] = (short)f2bf(x0.y);
        a[2] = (short)f2bf(x0.z); a[3] = (short)f2bf(x0.w);
        a[4] = (short)f2bf(x1.x); a[5] = (short)f2bf(x1.y);
        a[6] = (short)f2bf(x1.z); a[7] = (short)f2bf(x1.w);
        afrag[s] = a;
    }

    f32x4 acc[8];
    #pragma unroll
    for (int c = 0; c < 8; ++c) { f32x4 z = {0.f, 0.f, 0.f, 0.f}; acc[c] = z; }

    #pragma unroll
    for (int s = 0; s < 4; ++s) {
        const int kc = s * 4 + q;
        #pragma unroll
        for (int c = 0; c < 8; ++c) {
            const int n = c * 16 + m;
            short8 bfrag = *(const short8*)&Wb[n * F + ((kc ^ m) * 8)];
            acc[c] = __builtin_amdgcn_mfma_f32_16x16x32_bf16(
                afrag[s], bfrag, acc[c], 0, 0, 0);
        }
    }

    #pragma unroll
    for (int c = 0; c < 8; ++c) {
        const float bc = bias[c * 16 + m];
        #pragma unroll
        for (int r = 0; r < 4; ++r) {
            out[(size_t)(r0 + q * 4 + r) * F + c * 16 + m] = acc[c][r] + bc;
        }
    }
}

// ---------------------------------------------------------------------------
// Parachute fallback (tiny ws): R1 atomic scatter + fp32 VALU transform.
// ---------------------------------------------------------------------------
__global__ __launch_bounds__(256) void scatter_kernel(
    const float* __restrict__ feat, const float* __restrict__ out_norm,
    const int* __restrict__ src, const int* __restrict__ dst,
    float* __restrict__ agg)
{
    const int wave = threadIdx.x >> 6;
    const int lane = threadIdx.x & 63;
    const int e = blockIdx.x * 4 + wave;
    const int s = src[e];
    const int d = dst[e];
    const float rn = 1.0f / out_norm[s];
    const float2 v = ((const float2*)(feat + (size_t)s * F))[lane];
    float* ap = agg + (size_t)d * F + lane * 2;
    unsafeAtomicAdd(ap,     v.x * rn);
    unsafeAtomicAdd(ap + 1, v.y * rn);
}

__global__ __launch_bounds__(256) void transform_kernel(
    float* __restrict__ out, const float* __restrict__ in_norm,
    const float* __restrict__ W, const float* __restrict__ bias)
{
    __shared__ float Wt[F * F];
    const int t = threadIdx.x;
    #pragma unroll
    for (int i = 0; i < (F * F) / 256; ++i) {
        int idx = t + i * 256;
        int j = idx >> 7;
        int k = idx & (F - 1);
        Wt[k * F + j] = W[idx];
    }
    __syncthreads();
    const int wave = t >> 6, lane = t & 63;
    const float b0 = bias[lane];
    const float b1 = bias[lane + 64];
    const int ngroups = N_NODES / 16;
    for (int g = blockIdx.x; g < ngroups; g += gridDim.x) {
        const int r = g * 16 + wave * 4;
        const float4* a0 = (const float4*)(out + (size_t)r * F);
        const float4* a1 = a0 + F / 4;
        const float4* a2 = a0 + 2 * (F / 4);
        const float4* a3 = a0 + 3 * (F / 4);
        float acc00 = 0.f, acc01 = 0.f, acc10 = 0.f, acc11 = 0.f;
        float acc20 = 0.f, acc21 = 0.f, acc30 = 0.f, acc31 = 0.f;
        for (int k4 = 0; k4 < F / 4; ++k4) {
            const float4 x0 = a0[k4]; const float4 x1 = a1[k4];
            const float4 x2 = a2[k4]; const float4 x3 = a3[k4];
            const float xs0[4] = {x0.x, x0.y, x0.z, x0.w};
            const float xs1[4] = {x1.x, x1.y, x1.z, x1.w};
            const float xs2[4] = {x2.x, x2.y, x2.z, x2.w};
            const float xs3[4] = {x3.x, x3.y, x3.z, x3.w};
            #pragma unroll
            for (int kk = 0; kk < 4; ++kk) {
                const int k = k4 * 4 + kk;
                const float w0 = Wt[k * F + lane];
                const float w1 = Wt[k * F + 64 + lane];
                acc00 = fmaf(xs0[kk], w0, acc00); acc01 = fmaf(xs0[kk], w1, acc01);
                acc10 = fmaf(xs1[kk], w0, acc10); acc11 = fmaf(xs1[kk], w1, acc11);
                acc20 = fmaf(xs2[kk], w0, acc20); acc21 = fmaf(xs2[kk], w1, acc21);
                acc30 = fmaf(xs3[kk], w0, acc30); acc31 = fmaf(xs3[kk], w1, acc31);
            }
        }
        const float i0 = 1.0f / in_norm[r + 0];
        const float i1 = 1.0f / in_norm[r + 1];
        const float i2 = 1.0f / in_norm[r + 2];
        const float i3 = 1.0f / in_norm[r + 3];
        out[(size_t)(r + 0) * F + lane]      = acc00 * i0 + b0;
        out[(size_t)(r + 0) * F + 64 + lane] = acc01 * i0 + b1;
        out[(size_t)(r + 1) * F + lane]      = acc10 * i1 + b0;
        out[(size_t)(r + 1) * F + 64 + lane] = acc11 * i1 + b1;
        out[(size_t)(r + 2) * F + lane]      = acc20 * i2 + b0;
        out[(size_t)(r + 2) * F + 64 + lane] = acc21 * i2 + b1;
        out[(size_t)(r + 3) * F + lane]      = acc30 * i3 + b0;
        out[(size_t)(r + 3) * F + 64 + lane] = acc31 * i3 + b1;
    }
}

extern "C" void kernel_launch(void* const* d_in, const int* in_sizes, int n_in,
                              void* d_out, int out_size, void* d_ws, size_t ws_size,
                              hipStream_t stream) {
    const float* feat     = (const float*)d_in[0];
    const float* in_norm  = (const float*)d_in[1];
    const float* out_norm = (const float*)d_in[2];
    const int*   src      = (const int*)d_in[3];
    const int*   dst      = (const int*)d_in[4];
    const float* W        = (const float*)d_in[5];
    const float* b        = (const float*)d_in[6];
    float* out = (float*)d_out;

    if (ws_size >= (size_t)WS_V6) {
        char* w = (char*)d_ws;
        int*            pool   = (int*)(w + 0);
        int*            base_t = (int*)(w + 6801408);
        int*            btot   = (int*)(w + 7115008);
        unsigned short* h      = (unsigned short*)(w + 7117056);

        prep_chist_kernel<<<(N_NODES * 32) / 256, 256, 0, stream>>>(
            feat, out_norm, dst, h, base_t);
        cscan1_kernel<<<NB_C, 64, 0, stream>>>(base_t, btot);
        binscatter_kernel<<<NBLK_BIN, 256, 0, stream>>>(src, dst, base_t, btot, pool);
        fsort_gather_kernel<<<NB_C, 1024, 0, stream>>>(pool, btot, h, in_norm, out);
        transform_mfma_kernel<<<(NGROUP + 3) / 4, 256, 0, stream>>>(out, W, b);
    } else {
        hipMemsetAsync(out, 0, (size_t)N_NODES * F * sizeof(float), stream);
        scatter_kernel<<<N_EDGES / 4, 256, 0, stream>>>(feat, out_norm, src, dst, out);
        transform_kernel<<<2048, 256, 0, stream>>>(out, in_norm, W, b);
    }
}

// Round 2
// 229.714 us; speedup vs baseline: 1.1062x; 1.0490x over previous
//
#include <hip/hip_runtime.h>

#define N_NODES 100000
#define N_EDGES 1600000
#define F 128
#define NB2 391             // fine buckets = ceil(N_NODES/256)
#define BSZ 256             // nodes per bucket
#define CHUNK 4000
#define NBLK_BIN 400        // 400 * 4000 = 1.6M exact
#define CAP2 5440           // bucket LDS capacity (mean 4096, sigma 64, +20 sigma)
#define NGROUP 6250         // N_NODES / 16

// ---------------- workspace layout (bytes) ----------------
// pool   : N_EDGES ints    @ 0        (6,400,000)
// base_t : 391*400 ints    @ 6400000  (625,600)   bucket-major count matrix
// btot   : 512 ints        @ 7025600  (2,048)
// h      : N*128 bf16      @ 7027712  (25,600,000)
// total 32,627,712 (< 32,717,056 proven available)
#define WS_V7 32627712

typedef __attribute__((ext_vector_type(8))) short short8;
typedef __attribute__((ext_vector_type(4))) float f32x4;

__device__ __forceinline__ unsigned short f2bf(float f) {
    unsigned u = __float_as_uint(f);
    return (unsigned short)((u + 0x7fffu + ((u >> 16) & 1u)) >> 16);
}

// ---------------------------------------------------------------------------
// prep + chist fused: all blocks do h[i][j] = bf16(feat[i][j]/out_norm[i]);
// blocks 0..399 additionally histogram their 4000-edge chunk into 391 fine
// buckets (dst>>8), bucket-major output base_t[bucket*400 + blk].
// ---------------------------------------------------------------------------
__global__ __launch_bounds__(256) void prep_chist_kernel(
    const float* __restrict__ feat, const float* __restrict__ out_norm,
    const int* __restrict__ dst,
    unsigned short* __restrict__ h, int* __restrict__ base_t)
{
    __shared__ int c[NB2];
    const int t = threadIdx.x;
    const bool do_hist = (blockIdx.x < NBLK_BIN);
    if (do_hist) {
        for (int i = t; i < NB2; i += 256) c[i] = 0;
        __syncthreads();
    }
    int q = blockIdx.x * 256 + t;      // grid exact: N*32/256
    int row = q >> 5;
    float r = 1.0f / out_norm[row];
    float4 v = ((const float4*)feat)[q];
    ushort4 o;
    o.x = f2bf(v.x * r); o.y = f2bf(v.y * r);
    o.z = f2bf(v.z * r); o.w = f2bf(v.w * r);
    ((ushort4*)h)[q] = o;
    if (do_hist) {
        int e0 = blockIdx.x * CHUNK;
        for (int i = t; i < CHUNK; i += 256)
            atomicAdd(&c[dst[e0 + i] >> 8], 1);
        __syncthreads();
        for (int i = t; i < NB2; i += 256)
            base_t[i * NBLK_BIN + blockIdx.x] = c[i];
    }
}

// ---------------------------------------------------------------------------
// Phase 2: per-bucket exclusive scan over its 400 per-block counts.
// One wave per bucket, shuffle prefix over contiguous ints. Emits bucket total.
// ---------------------------------------------------------------------------
__global__ __launch_bounds__(64) void cscan1_kernel(
    int* __restrict__ base_t, int* __restrict__ btot)
{
    int b = blockIdx.x, l = threadIdx.x;
    int carry = 0;
    #pragma unroll
    for (int r = 0; r < 7; ++r) {            // 7*64 = 448 >= 400
        int idx = r * 64 + l;
        bool ok = idx < NBLK_BIN;
        int v = ok ? base_t[b * NBLK_BIN + idx] : 0;
        int incl = v;
        #pragma unroll
        for (int off = 1; off < 64; off <<= 1) {
            int n = __shfl_up(incl, off);
            if (l >= off) incl += n;
        }
        if (ok) base_t[b * NBLK_BIN + idx] = incl - v + carry;
        carry += __shfl(incl, 63);
    }
    if (l == 0) btot[b] = carry;
}

// ---------------------------------------------------------------------------
// Phase 3: scatter packed edges ((dst&255)<<17 | src) bucket-grouped.
// Bucket bases recomputed per block from btot (512-wide LDS ladder scan).
// ---------------------------------------------------------------------------
__global__ __launch_bounds__(512) void binscatter_kernel(
    const int* __restrict__ src, const int* __restrict__ dst,
    const int* __restrict__ base_t, const int* __restrict__ btot,
    int* __restrict__ pool)
{
    __shared__ int cba[NB2];
    __shared__ int sm[512];
    int t = threadIdx.x, blk = blockIdx.x;
    int v = (t < NB2) ? btot[t] : 0;
    sm[t] = v;
    __syncthreads();
    for (int off = 1; off < 512; off <<= 1) {
        int x = (t >= off) ? sm[t - off] : 0;
        __syncthreads();
        sm[t] += x;
        __syncthreads();
    }
    if (t < NB2) cba[t] = (sm[t] - v) + base_t[t * NBLK_BIN + blk];
    __syncthreads();
    int e0 = blk * CHUNK;
    for (int i = t; i < CHUNK; i += 512) {
        int d = dst[e0 + i];
        int s = src[e0 + i];
        int b = d >> 8;
        int pos = atomicAdd(&cba[b], 1);
        pool[pos] = ((d & 255) << 17) | s;
    }
}

// ---------------------------------------------------------------------------
// Phase 4 (fused finesort + gather): per-bucket counting sort entirely in
// LDS (pairs -> sorted src lists, no global write-back), then each wave
// gathers h rows for 16 of the bucket's 256 nodes straight from the LDS
// lists and writes agg (1/in_norm folded). ~47 KB LDS -> 2 blocks/CU;
// grid 391 blocks -> all co-resident, ~24 waves/CU (vs 16 at 512-node
// buckets, which starved the latency-bound gather — R1 post-mortem).
// ---------------------------------------------------------------------------
__global__ __launch_bounds__(1024) void fsort_gather_kernel(
    const int* __restrict__ pool, const int* __restrict__ btot,
    const unsigned short* __restrict__ h, const float* __restrict__ in_norm,
    float* __restrict__ agg)
{
    __shared__ int pairs[CAP2];
    __shared__ int sorted_s[CAP2];
    __shared__ int fcnt[BSZ];
    __shared__ int s0[BSZ];
    __shared__ int sexcl[BSZ];
    __shared__ int wsum[4];
    __shared__ int woff[4];
    __shared__ int sbeg[1];

    const int t = threadIdx.x, b = blockIdx.x;
    const int lane = t & 63, wv = t >> 6;

    // beg = sum_{j<b} btot[j]  (wave 0 only, shuffle reduce)
    if (t < 64) {
        int acc = 0;
        for (int j = t; j < NB2; j += 64) acc += (j < b) ? btot[j] : 0;
        #pragma unroll
        for (int off = 32; off; off >>= 1) acc += __shfl_xor(acc, off);
        if (t == 0) sbeg[0] = acc;
    }
    if (t < BSZ) fcnt[t] = 0;
    __syncthreads();
    const int beg = sbeg[0];
    int cnt = btot[b];
    if (cnt > CAP2) cnt = CAP2;   // statistically unreachable

    for (int i = t; i < cnt; i += 1024) pairs[i] = pool[beg + i];
    __syncthreads();
    for (int i = t; i < cnt; i += 1024) atomicAdd(&fcnt[pairs[i] >> 17], 1);
    __syncthreads();

    // inclusive scan of fcnt[256]: per-wave shuffle scan + 4-wide fixup
    if (t < BSZ) {
        int v = fcnt[t];
        int incl = v;
        #pragma unroll
        for (int off = 1; off < 64; off <<= 1) {
            int n = __shfl_up(incl, off);
            if (lane >= off) incl += n;
        }
        s0[t] = incl;
        if (lane == 63) wsum[wv] = incl;
    }
    __syncthreads();
    if (t < 64) {
        int v = (t < 4) ? wsum[t] : 0;
        int incl = v;
        #pragma unroll
        for (int off = 1; off < 4; off <<= 1) {
            int n = __shfl_up(incl, off);
            if (lane >= off) incl += n;
        }
        if (t < 4) woff[t] = incl - v;
    }
    __syncthreads();
    if (t < BSZ) {
        int sv = s0[t] + woff[t >> 6];
        s0[t] = sv;                 // local inclusive END per node
        sexcl[t] = sv - fcnt[t];    // local scatter cursor
    }
    __syncthreads();

    // counting-sort scatter into LDS
    for (int i = t; i < cnt; i += 1024) {
        int p = pairs[i];
        int pos = atomicAdd(&sexcl[p >> 17], 1);
        sorted_s[pos] = p & 0x1FFFF;
    }
    __syncthreads();

    // gather: wave wv owns local nodes [wv*16, wv*16+16)
    const unsigned* hp = (const unsigned*)h;
    const int node0 = b << 8;
    const int nEnd = wv * 16 + 16;
    for (int nl = wv * 16; nl < nEnd; ++nl) {
        const int node = node0 + nl;
        if (node >= N_NODES) break;
        const int start = (nl == 0) ? 0 : s0[nl - 1];
        const int end = s0[nl];
        float ax = 0.f, ay = 0.f;
        int e = start;
        for (; e + 7 < end; e += 8) {
            unsigned u0 = hp[(size_t)sorted_s[e]     * 64 + lane];
            unsigned u1 = hp[(size_t)sorted_s[e + 1] * 64 + lane];
            unsigned u2 = hp[(size_t)sorted_s[e + 2] * 64 + lane];
            unsigned u3 = hp[(size_t)sorted_s[e + 3] * 64 + lane];
            unsigned u4 = hp[(size_t)sorted_s[e + 4] * 64 + lane];
            unsigned u5 = hp[(size_t)sorted_s[e + 5] * 64 + lane];
            unsigned u6 = hp[(size_t)sorted_s[e + 6] * 64 + lane];
            unsigned u7 = hp[(size_t)sorted_s[e + 7] * 64 + lane];
            ax += __uint_as_float(u0 << 16) + __uint_as_float(u1 << 16)
                + __uint_as_float(u2 << 16) + __uint_as_float(u3 << 16)
                + __uint_as_float(u4 << 16) + __uint_as_float(u5 << 16)
                + __uint_as_float(u6 << 16) + __uint_as_float(u7 << 16);
            ay += __uint_as_float(u0 & 0xffff0000u) + __uint_as_float(u1 & 0xffff0000u)
                + __uint_as_float(u2 & 0xffff0000u) + __uint_as_float(u3 & 0xffff0000u)
                + __uint_as_float(u4 & 0xffff0000u) + __uint_as_float(u5 & 0xffff0000u)
                + __uint_as_float(u6 & 0xffff0000u) + __uint_as_float(u7 & 0xffff0000u);
        }
        for (; e + 3 < end; e += 4) {
            unsigned u0 = hp[(size_t)sorted_s[e]     * 64 + lane];
            unsigned u1 = hp[(size_t)sorted_s[e + 1] * 64 + lane];
            unsigned u2 = hp[(size_t)sorted_s[e + 2] * 64 + lane];
            unsigned u3 = hp[(size_t)sorted_s[e + 3] * 64 + lane];
            ax += __uint_as_float(u0 << 16) + __uint_as_float(u1 << 16)
                + __uint_as_float(u2 << 16) + __uint_as_float(u3 << 16);
            ay += __uint_as_float(u0 & 0xffff0000u) + __uint_as_float(u1 & 0xffff0000u)
                + __uint_as_float(u2 & 0xffff0000u) + __uint_as_float(u3 & 0xffff0000u);
        }
        for (; e < end; ++e) {
            unsigned u = hp[(size_t)sorted_s[e] * 64 + lane];
            ax += __uint_as_float(u << 16);
            ay += __uint_as_float(u & 0xffff0000u);
        }
        const float rin = 1.0f / in_norm[node];
        float2 o; o.x = ax * rin; o.y = ay * rin;
        ((float2*)agg)[(size_t)node * 64 + lane] = o;
    }
}

// ---------------------------------------------------------------------------
// MFMA transform (in-place on d_out, R3/R4-proven): out = agg @ W^T + b.
// rin already applied by gather. 32 KB LDS, chunk-XOR swizzle.
// ---------------------------------------------------------------------------
__global__ __launch_bounds__(256) void transform_mfma_kernel(
    float* __restrict__ out, const float* __restrict__ W,
    const float* __restrict__ bias)
{
    __shared__ short Wb[F * F];   // 32 KB bf16, chunk-XOR swizzled
    const int t = threadIdx.x;
    #pragma unroll
    for (int i = 0; i < 8; ++i) {
        int c = t + i * 256;
        int n = c >> 4, kc = c & 15;
        const float4* wp = (const float4*)(W + n * F + kc * 8);
        float4 w0 = wp[0], w1 = wp[1];
        short8 v;
        v[0] = (short)f2bf(w0.x); v[1] = (short)f2bf(w0.y);
        v[2] = (short)f2bf(w0.z); v[3] = (short)f2bf(w0.w);
        v[4] = (short)f2bf(w1.x); v[5] = (short)f2bf(w1.y);
        v[6] = (short)f2bf(w1.z); v[7] = (short)f2bf(w1.w);
        *(short8*)&Wb[n * F + ((kc ^ (n & 15)) * 8)] = v;
    }
    __syncthreads();

    const int wave = t >> 6, lane = t & 63;
    const int wblk = blockIdx.x * 4 + wave;
    if (wblk >= NGROUP) return;
    const int r0 = wblk * 16;
    const int m = lane & 15, q = lane >> 4;
    const float4* arow = (const float4*)(out + (size_t)(r0 + m) * F);

    short8 afrag[4];
    #pragma unroll
    for (int s = 0; s < 4; ++s) {
        int k0 = s * 32 + q * 8;
        float4 x0 = arow[k0 >> 2];
        float4 x1 = arow[(k0 >> 2) + 1];
        short8 a;
        a[0] = (short)f2bf(x0.x); a[1] = (short)f2bf(x0.y);
        a[2] = (short)f2bf(x0.z); a[3] = (short)f2bf(x0.w);
        a[4] = (short)f2bf(x1.x); a[5] = (short)f2bf(x1.y);
        a[6] = (short)f2bf(x1.z); a[7] = (short)f2bf(x1.w);
        afrag[s] = a;
    }

    f32x4 acc[8];
    #pragma unroll
    for (int c = 0; c < 8; ++c) { f32x4 z = {0.f, 0.f, 0.f, 0.f}; acc[c] = z; }

    #pragma unroll
    for (int s = 0; s < 4; ++s) {
        const int kc = s * 4 + q;
        #pragma unroll
        for (int c = 0; c < 8; ++c) {
            const int n = c * 16 + m;
            short8 bfrag = *(const short8*)&Wb[n * F + ((kc ^ m) * 8)];
            acc[c] = __builtin_amdgcn_mfma_f32_16x16x32_bf16(
                afrag[s], bfrag, acc[c], 0, 0, 0);
        }
    }

    #pragma unroll
    for (int c = 0; c < 8; ++c) {
        const float bc = bias[c * 16 + m];
        #pragma unroll
        for (int r = 0; r < 4; ++r) {
            out[(size_t)(r0 + q * 4 + r) * F + c * 16 + m] = acc[c][r] + bc;
        }
    }
}

// ---------------------------------------------------------------------------
// Parachute fallback (tiny ws): R1 atomic scatter + fp32 VALU transform.
// ---------------------------------------------------------------------------
__global__ __launch_bounds__(256) void scatter_kernel(
    const float* __restrict__ feat, const float* __restrict__ out_norm,
    const int* __restrict__ src, const int* __restrict__ dst,
    float* __restrict__ agg)
{
    const int wave = threadIdx.x >> 6;
    const int lane = threadIdx.x & 63;
    const int e = blockIdx.x * 4 + wave;
    const int s = src[e];
    const int d = dst[e];
    const float rn = 1.0f / out_norm[s];
    const float2 v = ((const float2*)(feat + (size_t)s * F))[lane];
    float* ap = agg + (size_t)d * F + lane * 2;
    unsafeAtomicAdd(ap,     v.x * rn);
    unsafeAtomicAdd(ap + 1, v.y * rn);
}

__global__ __launch_bounds__(256) void transform_kernel(
    float* __restrict__ out, const float* __restrict__ in_norm,
    const float* __restrict__ W, const float* __restrict__ bias)
{
    __shared__ float Wt[F * F];
    const int t = threadIdx.x;
    #pragma unroll
    for (int i = 0; i < (F * F) / 256; ++i) {
        int idx = t + i * 256;
        int j = idx >> 7;
        int k = idx & (F - 1);
        Wt[k * F + j] = W[idx];
    }
    __syncthreads();
    const int wave = t >> 6, lane = t & 63;
    const float b0 = bias[lane];
    const float b1 = bias[lane + 64];
    const int ngroups = N_NODES / 16;
    for (int g = blockIdx.x; g < ngroups; g += gridDim.x) {
        const int r = g * 16 + wave * 4;
        const float4* a0 = (const float4*)(out + (size_t)r * F);
        const float4* a1 = a0 + F / 4;
        const float4* a2 = a0 + 2 * (F / 4);
        const float4* a3 = a0 + 3 * (F / 4);
        float acc00 = 0.f, acc01 = 0.f, acc10 = 0.f, acc11 = 0.f;
        float acc20 = 0.f, acc21 = 0.f, acc30 = 0.f, acc31 = 0.f;
        for (int k4 = 0; k4 < F / 4; ++k4) {
            const float4 x0 = a0[k4]; const float4 x1 = a1[k4];
            const float4 x2 = a2[k4]; const float4 x3 = a3[k4];
            const float xs0[4] = {x0.x, x0.y, x0.z, x0.w};
            const float xs1[4] = {x1.x, x1.y, x1.z, x1.w};
            const float xs2[4] = {x2.x, x2.y, x2.z, x2.w};
            const float xs3[4] = {x3.x, x3.y, x3.z, x3.w};
            #pragma unroll
            for (int kk = 0; kk < 4; ++kk) {
                const int k = k4 * 4 + kk;
                const float w0 = Wt[k * F + lane];
                const float w1 = Wt[k * F + 64 + lane];
                acc00 = fmaf(xs0[kk], w0, acc00); acc01 = fmaf(xs0[kk], w1, acc01);
                acc10 = fmaf(xs1[kk], w0, acc10); acc11 = fmaf(xs1[kk], w1, acc11);
                acc20 = fmaf(xs2[kk], w0, acc20); acc21 = fmaf(xs2[kk], w1, acc21);
                acc30 = fmaf(xs3[kk], w0, acc30); acc31 = fmaf(xs3[kk], w1, acc31);
            }
        }
        const float i0 = 1.0f / in_norm[r + 0];
        const float i1 = 1.0f / in_norm[r + 1];
        const float i2 = 1.0f / in_norm[r + 2];
        const float i3 = 1.0f / in_norm[r + 3];
        out[(size_t)(r + 0) * F + lane]      = acc00 * i0 + b0;
        out[(size_t)(r + 0) * F + 64 + lane] = acc01 * i0 + b1;
        out[(size_t)(r + 1) * F + lane]      = acc10 * i1 + b0;
        out[(size_t)(r + 1) * F + 64 + lane] = acc11 * i1 + b1;
        out[(size_t)(r + 2) * F + lane]      = acc20 * i2 + b0;
        out[(size_t)(r + 2) * F + 64 + lane] = acc21 * i2 + b1;
        out[(size_t)(r + 3) * F + lane]      = acc30 * i3 + b0;
        out[(size_t)(r + 3) * F + 64 + lane] = acc31 * i3 + b1;
    }
}

extern "C" void kernel_launch(void* const* d_in, const int* in_sizes, int n_in,
                              void* d_out, int out_size, void* d_ws, size_t ws_size,
                              hipStream_t stream) {
    const float* feat     = (const float*)d_in[0];
    const float* in_norm  = (const float*)d_in[1];
    const float* out_norm = (const float*)d_in[2];
    const int*   src      = (const int*)d_in[3];
    const int*   dst      = (const int*)d_in[4];
    const float* W        = (const float*)d_in[5];
    const float* b        = (const float*)d_in[6];
    float* out = (float*)d_out;

    if (ws_size >= (size_t)WS_V7) {
        char* w = (char*)d_ws;
        int*            pool   = (int*)(w + 0);
        int*            base_t = (int*)(w + 6400000);
        int*            btot   = (int*)(w + 7025600);
        unsigned short* h      = (unsigned short*)(w + 7027712);

        prep_chist_kernel<<<(N_NODES * 32) / 256, 256, 0, stream>>>(
            feat, out_norm, dst, h, base_t);
        cscan1_kernel<<<NB2, 64, 0, stream>>>(base_t, btot);
        binscatter_kernel<<<NBLK_BIN, 512, 0, stream>>>(src, dst, base_t, btot, pool);
        fsort_gather_kernel<<<NB2, 1024, 0, stream>>>(pool, btot, h, in_norm, out);
        transform_mfma_kernel<<<(NGROUP + 3) / 4, 256, 0, stream>>>(out, W, b);
    } else {
        hipMemsetAsync(out, 0, (size_t)N_NODES * F * sizeof(float), stream);
        scatter_kernel<<<N_EDGES / 4, 256, 0, stream>>>(feat, out_norm, src, dst, out);
        transform_kernel<<<2048, 256, 0, stream>>>(out, in_norm, W, b);
    }
}

// Round 4
// 215.812 us; speedup vs baseline: 1.1775x; 1.0644x over previous
//
#include <hip/hip_runtime.h>

#define N_NODES 100000
#define N_EDGES 1600000
#define F 128
#define NB2 391             // fine buckets = ceil(N_NODES/256)
#define BSZ 256             // nodes per bucket
#define CHUNK 4000
#define NBLK_BIN 400        // 400 * 4000 = 1.6M exact
#define CAP2 5440           // bucket LDS capacity (mean 4096, sigma 64, +20 sigma)
#define NGROUP 6250         // N_NODES / 16
#define NPREP_BLK 1563      // ceil(NGROUP/4) wave-tiles of 16 rows

// ---------------- workspace layout (bytes) ----------------
// pool   : N_EDGES ints    @ 0        (6,400,000)
// base_t : 391*400 ints    @ 6400000  (625,600)   bucket-major count matrix
// btot   : 512 ints        @ 7025600  (2,048)
// g      : N*128 bf16      @ 7027712  (25,600,000)   g = bf16((feat/out_norm) @ W^T)
// total 32,627,712 (< 32,717,056 proven available)
#define WS_V8 32627712

typedef __attribute__((ext_vector_type(8))) short short8;
typedef __attribute__((ext_vector_type(4))) float f32x4;

__device__ __forceinline__ unsigned short f2bf(float f) {
    unsigned u = __float_as_uint(f);
    return (unsigned short)((u + 0x7fffu + ((u >> 16) & 1u)) >> 16);
}

// ---------------------------------------------------------------------------
// prep + GEMM + chist fused (R3): g = bf16((feat/out_norm) @ W^T).
// Linearity lets the W-transform commute through the edge aggregation, so
// the old 102 MB agg round-trip (transform_mfma) disappears entirely.
// Each wave owns 16 rows (same fragment/MFMA structure as the old
// transform_mfma); blocks 0..399 additionally histogram their 4000-edge
// chunk into 391 fine buckets (dst>>8), bucket-major base_t[b*400+blk].
// ---------------------------------------------------------------------------
__global__ __launch_bounds__(256) void prep_gemm_chist_kernel(
    const float* __restrict__ feat, const float* __restrict__ out_norm,
    const int* __restrict__ dst, const float* __restrict__ W,
    unsigned short* __restrict__ g, int* __restrict__ base_t)
{
    __shared__ short Wb[F * F];   // 32 KB bf16, chunk-XOR swizzled
    __shared__ int c[NB2];
    const int t = threadIdx.x;
    const bool do_hist = (blockIdx.x < NBLK_BIN);
    if (do_hist) {
        for (int i = t; i < NB2; i += 256) c[i] = 0;
    }
    #pragma unroll
    for (int i = 0; i < 8; ++i) {
        int cc = t + i * 256;
        int n = cc >> 4, kc = cc & 15;
        const float4* wp = (const float4*)(W + n * F + kc * 8);
        float4 w0 = wp[0], w1 = wp[1];
        short8 v;
        v[0] = (short)f2bf(w0.x); v[1] = (short)f2bf(w0.y);
        v[2] = (short)f2bf(w0.z); v[3] = (short)f2bf(w0.w);
        v[4] = (short)f2bf(w1.x); v[5] = (short)f2bf(w1.y);
        v[6] = (short)f2bf(w1.z); v[7] = (short)f2bf(w1.w);
        *(short8*)&Wb[n * F + ((kc ^ (n & 15)) * 8)] = v;
    }
    __syncthreads();

    // histogram (memory-latency heavy; overlaps with GEMM below via waves)
    if (do_hist) {
        int e0 = blockIdx.x * CHUNK;
        for (int i = t; i < CHUNK; i += 256)
            atomicAdd(&c[dst[e0 + i] >> 8], 1);
    }

    const int wave = t >> 6, lane = t & 63;
    const int wblk = blockIdx.x * 4 + wave;
    if (wblk < NGROUP) {
        const int r0 = wblk * 16;
        const int m = lane & 15, q = lane >> 4;
        const float* arow = feat + (size_t)(r0 + m) * F;
        const float rscale = 1.0f / out_norm[r0 + m];

        short8 afrag[4];
        #pragma unroll
        for (int s = 0; s < 4; ++s) {
            int k0 = s * 32 + q * 8;
            float4 x0 = *(const float4*)(arow + k0);
            float4 x1 = *(const float4*)(arow + k0 + 4);
            short8 a;
            a[0] = (short)f2bf(x0.x * rscale); a[1] = (short)f2bf(x0.y * rscale);
            a[2] = (short)f2bf(x0.z * rscale); a[3] = (short)f2bf(x0.w * rscale);
            a[4] = (short)f2bf(x1.x * rscale); a[5] = (short)f2bf(x1.y * rscale);
            a[6] = (short)f2bf(x1.z * rscale); a[7] = (short)f2bf(x1.w * rscale);
            afrag[s] = a;
        }

        f32x4 acc[8];
        #pragma unroll
        for (int cc = 0; cc < 8; ++cc) { f32x4 z = {0.f, 0.f, 0.f, 0.f}; acc[cc] = z; }

        #pragma unroll
        for (int s = 0; s < 4; ++s) {
            const int kc = s * 4 + q;
            #pragma unroll
            for (int cc = 0; cc < 8; ++cc) {
                const int n = cc * 16 + m;
                short8 bfrag = *(const short8*)&Wb[n * F + ((kc ^ m) * 8)];
                acc[cc] = __builtin_amdgcn_mfma_f32_16x16x32_bf16(
                    afrag[s], bfrag, acc[cc], 0, 0, 0);
            }
        }

        #pragma unroll
        for (int cc = 0; cc < 8; ++cc) {
            #pragma unroll
            for (int r = 0; r < 4; ++r) {
                g[(size_t)(r0 + q * 4 + r) * F + cc * 16 + m] = f2bf(acc[cc][r]);
            }
        }
    }

    __syncthreads();
    if (do_hist) {
        for (int i = t; i < NB2; i += 256)
            base_t[i * NBLK_BIN + blockIdx.x] = c[i];
    }
}

// ---------------------------------------------------------------------------
// Phase 2: per-bucket exclusive scan over its 400 per-block counts.
// One wave per bucket, shuffle prefix over contiguous ints. Emits bucket total.
// ---------------------------------------------------------------------------
__global__ __launch_bounds__(64) void cscan1_kernel(
    int* __restrict__ base_t, int* __restrict__ btot)
{
    int b = blockIdx.x, l = threadIdx.x;
    int carry = 0;
    #pragma unroll
    for (int r = 0; r < 7; ++r) {            // 7*64 = 448 >= 400
        int idx = r * 64 + l;
        bool ok = idx < NBLK_BIN;
        int v = ok ? base_t[b * NBLK_BIN + idx] : 0;
        int incl = v;
        #pragma unroll
        for (int off = 1; off < 64; off <<= 1) {
            int n = __shfl_up(incl, off);
            if (l >= off) incl += n;
        }
        if (ok) base_t[b * NBLK_BIN + idx] = incl - v + carry;
        carry += __shfl(incl, 63);
    }
    if (l == 0) btot[b] = carry;
}

// ---------------------------------------------------------------------------
// Phase 3: scatter packed edges ((dst&255)<<17 | src) bucket-grouped.
// Bucket bases recomputed per block from btot (512-wide LDS ladder scan).
// ---------------------------------------------------------------------------
__global__ __launch_bounds__(512) void binscatter_kernel(
    const int* __restrict__ src, const int* __restrict__ dst,
    const int* __restrict__ base_t, const int* __restrict__ btot,
    int* __restrict__ pool)
{
    __shared__ int cba[NB2];
    __shared__ int sm[512];
    int t = threadIdx.x, blk = blockIdx.x;
    int v = (t < NB2) ? btot[t] : 0;
    sm[t] = v;
    __syncthreads();
    for (int off = 1; off < 512; off <<= 1) {
        int x = (t >= off) ? sm[t - off] : 0;
        __syncthreads();
        sm[t] += x;
        __syncthreads();
    }
    if (t < NB2) cba[t] = (sm[t] - v) + base_t[t * NBLK_BIN + blk];
    __syncthreads();
    int e0 = blk * CHUNK;
    for (int i = t; i < CHUNK; i += 512) {
        int d = dst[e0 + i];
        int s = src[e0 + i];
        int b = d >> 8;
        int pos = atomicAdd(&cba[b], 1);
        pool[pos] = ((d & 255) << 17) | s;
    }
}

// ---------------------------------------------------------------------------
// Phase 4 (fused finesort + gather, R3: gathers g and writes FINAL out):
// per-bucket counting sort entirely in LDS, then each wave gathers g rows
// for 16 of the bucket's 256 nodes and writes out = agg_g * rin + bias.
// ~47 KB LDS -> 2 blocks/CU, 391 blocks all co-resident.
// ---------------------------------------------------------------------------
__global__ __launch_bounds__(1024) void fsort_gather_kernel(
    const int* __restrict__ pool, const int* __restrict__ btot,
    const unsigned short* __restrict__ g, const float* __restrict__ in_norm,
    const float* __restrict__ bias, float* __restrict__ out)
{
    __shared__ int pairs[CAP2];
    __shared__ int sorted_s[CAP2];
    __shared__ int fcnt[BSZ];
    __shared__ int s0[BSZ];
    __shared__ int sexcl[BSZ];
    __shared__ int wsum[4];
    __shared__ int woff[4];
    __shared__ int sbeg[1];

    const int t = threadIdx.x, b = blockIdx.x;
    const int lane = t & 63, wv = t >> 6;

    // beg = sum_{j<b} btot[j]  (wave 0 only, shuffle reduce)
    if (t < 64) {
        int acc = 0;
        for (int j = t; j < NB2; j += 64) acc += (j < b) ? btot[j] : 0;
        #pragma unroll
        for (int off = 32; off; off >>= 1) acc += __shfl_xor(acc, off);
        if (t == 0) sbeg[0] = acc;
    }
    if (t < BSZ) fcnt[t] = 0;
    __syncthreads();
    const int beg = sbeg[0];
    int cnt = btot[b];
    if (cnt > CAP2) cnt = CAP2;   // statistically unreachable

    for (int i = t; i < cnt; i += 1024) pairs[i] = pool[beg + i];
    __syncthreads();
    for (int i = t; i < cnt; i += 1024) atomicAdd(&fcnt[pairs[i] >> 17], 1);
    __syncthreads();

    // inclusive scan of fcnt[256]: per-wave shuffle scan + 4-wide fixup
    if (t < BSZ) {
        int v = fcnt[t];
        int incl = v;
        #pragma unroll
        for (int off = 1; off < 64; off <<= 1) {
            int n = __shfl_up(incl, off);
            if (lane >= off) incl += n;
        }
        s0[t] = incl;
        if (lane == 63) wsum[wv] = incl;
    }
    __syncthreads();
    if (t < 64) {
        int v = (t < 4) ? wsum[t] : 0;
        int incl = v;
        #pragma unroll
        for (int off = 1; off < 4; off <<= 1) {
            int n = __shfl_up(incl, off);
            if (lane >= off) incl += n;
        }
        if (t < 4) woff[t] = incl - v;
    }
    __syncthreads();
    if (t < BSZ) {
        int sv = s0[t] + woff[t >> 6];
        s0[t] = sv;                 // local inclusive END per node
        sexcl[t] = sv - fcnt[t];    // local scatter cursor
    }
    __syncthreads();

    // counting-sort scatter into LDS
    for (int i = t; i < cnt; i += 1024) {
        int p = pairs[i];
        int pos = atomicAdd(&sexcl[p >> 17], 1);
        sorted_s[pos] = p & 0x1FFFF;
    }
    __syncthreads();

    // gather: wave wv owns local nodes [wv*16, wv*16+16)
    const unsigned* gp = (const unsigned*)g;
    const float2 bl = ((const float2*)bias)[lane];   // cols 2*lane, 2*lane+1
    const int node0 = b << 8;
    const int nEnd = wv * 16 + 16;
    for (int nl = wv * 16; nl < nEnd; ++nl) {
        const int node = node0 + nl;
        if (node >= N_NODES) break;
        const int start = (nl == 0) ? 0 : s0[nl - 1];
        const int end = s0[nl];
        float ax = 0.f, ay = 0.f;
        int e = start;
        for (; e + 7 < end; e += 8) {
            unsigned u0 = gp[(size_t)sorted_s[e]     * 64 + lane];
            unsigned u1 = gp[(size_t)sorted_s[e + 1] * 64 + lane];
            unsigned u2 = gp[(size_t)sorted_s[e + 2] * 64 + lane];
            unsigned u3 = gp[(size_t)sorted_s[e + 3] * 64 + lane];
            unsigned u4 = gp[(size_t)sorted_s[e + 4] * 64 + lane];
            unsigned u5 = gp[(size_t)sorted_s[e + 5] * 64 + lane];
            unsigned u6 = gp[(size_t)sorted_s[e + 6] * 64 + lane];
            unsigned u7 = gp[(size_t)sorted_s[e + 7] * 64 + lane];
            ax += __uint_as_float(u0 << 16) + __uint_as_float(u1 << 16)
                + __uint_as_float(u2 << 16) + __uint_as_float(u3 << 16)
                + __uint_as_float(u4 << 16) + __uint_as_float(u5 << 16)
                + __uint_as_float(u6 << 16) + __uint_as_float(u7 << 16);
            ay += __uint_as_float(u0 & 0xffff0000u) + __uint_as_float(u1 & 0xffff0000u)
                + __uint_as_float(u2 & 0xffff0000u) + __uint_as_float(u3 & 0xffff0000u)
                + __uint_as_float(u4 & 0xffff0000u) + __uint_as_float(u5 & 0xffff0000u)
                + __uint_as_float(u6 & 0xffff0000u) + __uint_as_float(u7 & 0xffff0000u);
        }
        for (; e + 3 < end; e += 4) {
            unsigned u0 = gp[(size_t)sorted_s[e]     * 64 + lane];
            unsigned u1 = gp[(size_t)sorted_s[e + 1] * 64 + lane];
            unsigned u2 = gp[(size_t)sorted_s[e + 2] * 64 + lane];
            unsigned u3 = gp[(size_t)sorted_s[e + 3] * 64 + lane];
            ax += __uint_as_float(u0 << 16) + __uint_as_float(u1 << 16)
                + __uint_as_float(u2 << 16) + __uint_as_float(u3 << 16);
            ay += __uint_as_float(u0 & 0xffff0000u) + __uint_as_float(u1 & 0xffff0000u)
                + __uint_as_float(u2 & 0xffff0000u) + __uint_as_float(u3 & 0xffff0000u);
        }
        for (; e < end; ++e) {
            unsigned u = gp[(size_t)sorted_s[e] * 64 + lane];
            ax += __uint_as_float(u << 16);
            ay += __uint_as_float(u & 0xffff0000u);
        }
        const float rin = 1.0f / in_norm[node];
        float2 o; o.x = ax * rin + bl.x; o.y = ay * rin + bl.y;
        ((float2*)out)[(size_t)node * 64 + lane] = o;
    }
}

// ---------------------------------------------------------------------------
// Parachute fallback (tiny ws): R1 atomic scatter + fp32 VALU transform.
// ---------------------------------------------------------------------------
__global__ __launch_bounds__(256) void scatter_kernel(
    const float* __restrict__ feat, const float* __restrict__ out_norm,
    const int* __restrict__ src, const int* __restrict__ dst,
    float* __restrict__ agg)
{
    const int wave = threadIdx.x >> 6;
    const int lane = threadIdx.x & 63;
    const int e = blockIdx.x * 4 + wave;
    const int s = src[e];
    const int d = dst[e];
    const float rn = 1.0f / out_norm[s];
    const float2 v = ((const float2*)(feat + (size_t)s * F))[lane];
    float* ap = agg + (size_t)d * F + lane * 2;
    unsafeAtomicAdd(ap,     v.x * rn);
    unsafeAtomicAdd(ap + 1, v.y * rn);
}

__global__ __launch_bounds__(256) void transform_kernel(
    float* __restrict__ out, const float* __restrict__ in_norm,
    const float* __restrict__ W, const float* __restrict__ bias)
{
    __shared__ float Wt[F * F];
    const int t = threadIdx.x;
    #pragma unroll
    for (int i = 0; i < (F * F) / 256; ++i) {
        int idx = t + i * 256;
        int j = idx >> 7;
        int k = idx & (F - 1);
        Wt[k * F + j] = W[idx];
    }
    __syncthreads();
    const int wave = t >> 6, lane = t & 63;
    const float b0 = bias[lane];
    const float b1 = bias[lane + 64];
    const int ngroups = N_NODES / 16;
    for (int gi = blockIdx.x; gi < ngroups; gi += gridDim.x) {
        const int r = gi * 16 + wave * 4;
        const float4* a0 = (const float4*)(out + (size_t)r * F);
        const float4* a1 = a0 + F / 4;
        const float4* a2 = a0 + 2 * (F / 4);
        const float4* a3 = a0 + 3 * (F / 4);
        float acc00 = 0.f, acc01 = 0.f, acc10 = 0.f, acc11 = 0.f;
        float acc20 = 0.f, acc21 = 0.f, acc30 = 0.f, acc31 = 0.f;
        for (int k4 = 0; k4 < F / 4; ++k4) {
            const float4 x0 = a0[k4]; const float4 x1 = a1[k4];
            const float4 x2 = a2[k4]; const float4 x3 = a3[k4];
            const float xs0[4] = {x0.x, x0.y, x0.z, x0.w};
            const float xs1[4] = {x1.x, x1.y, x1.z, x1.w};
            const float xs2[4] = {x2.x, x2.y, x2.z, x2.w};
            const float xs3[4] = {x3.x, x3.y, x3.z, x3.w};
            #pragma unroll
            for (int kk = 0; kk < 4; ++kk) {
                const int k = k4 * 4 + kk;
                const float w0 = Wt[k * F + lane];
                const float w1 = Wt[k * F + 64 + lane];
                acc00 = fmaf(xs0[kk], w0, acc00); acc01 = fmaf(xs0[kk], w1, acc01);
                acc10 = fmaf(xs1[kk], w0, acc10); acc11 = fmaf(xs1[kk], w1, acc11);
                acc20 = fmaf(xs2[kk], w0, acc20); acc21 = fmaf(xs2[kk], w1, acc21);
                acc30 = fmaf(xs3[kk], w0, acc30); acc31 = fmaf(xs3[kk], w1, acc31);
            }
        }
        const float i0 = 1.0f / in_norm[r + 0];
        const float i1 = 1.0f / in_norm[r + 1];
        const float i2 = 1.0f / in_norm[r + 2];
        const float i3 = 1.0f / in_norm[r + 3];
        out[(size_t)(r + 0) * F + lane]      = acc00 * i0 + b0;
        out[(size_t)(r + 0) * F + 64 + lane] = acc01 * i0 + b1;
        out[(size_t)(r + 1) * F + lane]      = acc10 * i1 + b0;
        out[(size_t)(r + 1) * F + 64 + lane] = acc11 * i1 + b1;
        out[(size_t)(r + 2) * F + lane]      = acc20 * i2 + b0;
        out[(size_t)(r + 2) * F + 64 + lane] = acc21 * i2 + b1;
        out[(size_t)(r + 3) * F + lane]      = acc30 * i3 + b0;
        out[(size_t)(r + 3) * F + 64 + lane] = acc31 * i3 + b1;
    }
}

extern "C" void kernel_launch(void* const* d_in, const int* in_sizes, int n_in,
                              void* d_out, int out_size, void* d_ws, size_t ws_size,
                              hipStream_t stream) {
    const float* feat     = (const float*)d_in[0];
    const float* in_norm  = (const float*)d_in[1];
    const float* out_norm = (const float*)d_in[2];
    const int*   src      = (const int*)d_in[3];
    const int*   dst      = (const int*)d_in[4];
    const float* W        = (const float*)d_in[5];
    const float* b        = (const float*)d_in[6];
    float* out = (float*)d_out;

    if (ws_size >= (size_t)WS_V8) {
        char* w = (char*)d_ws;
        int*            pool   = (int*)(w + 0);
        int*            base_t = (int*)(w + 6400000);
        int*            btot   = (int*)(w + 7025600);
        unsigned short* g      = (unsigned short*)(w + 7027712);

        prep_gemm_chist_kernel<<<NPREP_BLK, 256, 0, stream>>>(
            feat, out_norm, dst, W, g, base_t);
        cscan1_kernel<<<NB2, 64, 0, stream>>>(base_t, btot);
        binscatter_kernel<<<NBLK_BIN, 512, 0, stream>>>(src, dst, base_t, btot, pool);
        fsort_gather_kernel<<<NB2, 1024, 0, stream>>>(pool, btot, g, in_norm, b, out);
    } else {
        hipMemsetAsync(out, 0, (size_t)N_NODES * F * sizeof(float), stream);
        scatter_kernel<<<N_EDGES / 4, 256, 0, stream>>>(feat, out_norm, src, dst, out);
        transform_kernel<<<2048, 256, 0, stream>>>(out, in_norm, W, b);
    }
}

// Round 5
// 203.691 us; speedup vs baseline: 1.2476x; 1.0595x over previous
//
#include <hip/hip_runtime.h>

#define N_NODES 100000
#define N_EDGES 1600000
#define F 128
#define NB2 391             // fine buckets = ceil(N_NODES/256)
#define BSZ 256             // nodes per bucket
#define CHUNK 4000
#define CAPB 4576           // fixed bucket capacity (mean 4096, sigma 64, +7.5 sigma)
#define NGROUP 6250         // N_NODES / 16
#define FRONT_NSORT 400     // sort-role blocks (400 * 4000 = 1.6M exact)
#define FRONT_NBLK 1182     // 400 sort + 782 gemm (782*8 = 6256 >= NGROUP wave-tiles)

// ---------------- workspace layout (bytes) ----------------
// pool : NB2*CAPB ints @ 0        (7,156,864)  bucket-major, fixed capacity
// gcur : 391 ints      @ 7156864  (4,096 incl pad)  per-bucket fill counters
// g    : N*128 bf16    @ 7160960  (25,600,000)  g = bf16((feat/out_norm) @ W^T)
// total 32,760,960 (< 32,804,864 proven available)
#define WS_V9 32760960

typedef __attribute__((ext_vector_type(8))) short short8;
typedef __attribute__((ext_vector_type(4))) float f32x4;

__device__ __forceinline__ unsigned short f2bf(float f) {
    unsigned u = __float_as_uint(f);
    return (unsigned short)((u + 0x7fffu + ((u >> 16) & 1u)) >> 16);
}

struct SortSmem {
    int   tmpv[CHUNK];    // packed (dst&255)<<17 | src
    short tmpb[CHUNK];    // bucket id per edge
    int   sorted[CHUNK];  // bucket-sorted packed values
    int   cnt[NB2];
    int   off[NB2];       // exclusive local offsets
    int   cur[NB2];       // scatter cursors
    int   gb[NB2];        // reserved global base (within bucket slice)
    int   wsum[8];
};
union FrontSmem {
    short    Wb[F * F];   // 32 KB (gemm role)
    SortSmem sp;          // ~45.3 KB (sort role) -> union 45.3 KB
};

// ---------------------------------------------------------------------------
// front kernel (R5): block-role split.
//   blocks [0,400): in-LDS counting sort of a 4000-edge chunk by bucket
//     (dst>>8), global atomic range-reserve in gcur, coalesced run writes
//     into the fixed-capacity bucket-major pool. Replaces chist + cscan1 +
//     binscatter (which did 1.6M isolated 4B writes + a ladder scan/block).
//   blocks [400,1182): g = bf16((feat/out_norm) @ W^T), 8 wave-tiles of 16
//     rows per 512-thread block (proven MFMA structure from R4).
// ---------------------------------------------------------------------------
__global__ __launch_bounds__(512) void front_kernel(
    const float* __restrict__ feat, const float* __restrict__ out_norm,
    const int* __restrict__ src, const int* __restrict__ dst,
    const float* __restrict__ W,
    unsigned short* __restrict__ g, int* __restrict__ pool,
    int* __restrict__ gcur)
{
    __shared__ FrontSmem u;
    const int t = threadIdx.x;
    const int lane = t & 63, wv = t >> 6;

    if (blockIdx.x < FRONT_NSORT) {
        // ---------------- sort role ----------------
        SortSmem& S = u.sp;
        for (int i = t; i < NB2; i += 512) S.cnt[i] = 0;
        __syncthreads();
        const int e0 = blockIdx.x * CHUNK;
        for (int i = t; i < CHUNK; i += 512) {
            int d = dst[e0 + i];
            int s = src[e0 + i];
            int b = d >> 8;
            S.tmpv[i] = ((d & 255) << 17) | s;
            S.tmpb[i] = (short)b;
            atomicAdd(&S.cnt[b], 1);
        }
        __syncthreads();
        // two-level shuffle scan over NB2 (padded to 512)
        int v = (t < NB2) ? S.cnt[t] : 0;
        int incl = v;
        #pragma unroll
        for (int o = 1; o < 64; o <<= 1) {
            int n = __shfl_up(incl, o);
            if (lane >= o) incl += n;
        }
        if (lane == 63) S.wsum[wv] = incl;
        __syncthreads();
        if (t < 64) {
            int vv = (t < 8) ? S.wsum[t] : 0;
            int ii = vv;
            #pragma unroll
            for (int o = 1; o < 8; o <<= 1) {
                int n = __shfl_up(ii, o);
                if (lane >= o) ii += n;
            }
            if (t < 8) S.wsum[t] = ii - vv;   // exclusive wave offset
        }
        __syncthreads();
        if (t < NB2) {
            int excl = incl - v + S.wsum[wv];
            S.off[t] = excl;
            S.cur[t] = excl;
        }
        __syncthreads();
        // reserve global ranges (one atomic per nonempty (block,bucket))
        for (int j = t; j < NB2; j += 512) {
            int c = S.cnt[j];
            S.gb[j] = (c > 0) ? atomicAdd(&gcur[j], c) : 0;
        }
        __syncthreads();
        // local counting-sort scatter
        for (int i = t; i < CHUNK; i += 512) {
            int b = S.tmpb[i];
            int p = atomicAdd(&S.cur[b], 1);
            S.sorted[p] = S.tmpv[i];
        }
        __syncthreads();
        // coalesced copy-out: wave wv owns buckets wv, wv+8, ...
        for (int j = wv; j < NB2; j += 8) {
            int c = S.cnt[j];
            if (c == 0) continue;
            int base = S.gb[j];
            int avail = CAPB - base; if (avail < 0) avail = 0;
            int lim = (c < avail) ? c : avail;   // statistically always == c
            int o = S.off[j];
            int* dp = pool + j * CAPB + base;
            for (int k = lane; k < lim; k += 64) dp[k] = S.sorted[o + k];
        }
    } else {
        // ---------------- gemm role ----------------
        #pragma unroll
        for (int i = 0; i < 4; ++i) {
            int cc = t + i * 512;
            int n = cc >> 4, kc = cc & 15;
            const float4* wp = (const float4*)(W + n * F + kc * 8);
            float4 w0 = wp[0], w1 = wp[1];
            short8 vv;
            vv[0] = (short)f2bf(w0.x); vv[1] = (short)f2bf(w0.y);
            vv[2] = (short)f2bf(w0.z); vv[3] = (short)f2bf(w0.w);
            vv[4] = (short)f2bf(w1.x); vv[5] = (short)f2bf(w1.y);
            vv[6] = (short)f2bf(w1.z); vv[7] = (short)f2bf(w1.w);
            *(short8*)&u.Wb[n * F + ((kc ^ (n & 15)) * 8)] = vv;
        }
        __syncthreads();

        const int wblk = (blockIdx.x - FRONT_NSORT) * 8 + wv;
        if (wblk >= NGROUP) return;
        const int r0 = wblk * 16;
        const int m = lane & 15, q = lane >> 4;
        const float* arow = feat + (size_t)(r0 + m) * F;
        const float rscale = 1.0f / out_norm[r0 + m];

        short8 afrag[4];
        #pragma unroll
        for (int s = 0; s < 4; ++s) {
            int k0 = s * 32 + q * 8;
            float4 x0 = *(const float4*)(arow + k0);
            float4 x1 = *(const float4*)(arow + k0 + 4);
            short8 a;
            a[0] = (short)f2bf(x0.x * rscale); a[1] = (short)f2bf(x0.y * rscale);
            a[2] = (short)f2bf(x0.z * rscale); a[3] = (short)f2bf(x0.w * rscale);
            a[4] = (short)f2bf(x1.x * rscale); a[5] = (short)f2bf(x1.y * rscale);
            a[6] = (short)f2bf(x1.z * rscale); a[7] = (short)f2bf(x1.w * rscale);
            afrag[s] = a;
        }

        f32x4 acc[8];
        #pragma unroll
        for (int cc = 0; cc < 8; ++cc) { f32x4 z = {0.f, 0.f, 0.f, 0.f}; acc[cc] = z; }

        #pragma unroll
        for (int s = 0; s < 4; ++s) {
            const int kc = s * 4 + q;
            #pragma unroll
            for (int cc = 0; cc < 8; ++cc) {
                const int n = cc * 16 + m;
                short8 bfrag = *(const short8*)&u.Wb[n * F + ((kc ^ m) * 8)];
                acc[cc] = __builtin_amdgcn_mfma_f32_16x16x32_bf16(
                    afrag[s], bfrag, acc[cc], 0, 0, 0);
            }
        }

        #pragma unroll
        for (int cc = 0; cc < 8; ++cc) {
            #pragma unroll
            for (int r = 0; r < 4; ++r) {
                g[(size_t)(r0 + q * 4 + r) * F + cc * 16 + m] = f2bf(acc[cc][r]);
            }
        }
    }
}

// ---------------------------------------------------------------------------
// fsort_gather (R5: fixed-capacity pool -> no prefix prologue): per-bucket
// counting sort entirely in LDS, then each wave gathers g rows for 16 of the
// bucket's 256 nodes and writes out = agg_g * rin + bias. ~40 KB LDS,
// 391 blocks, 2 blocks/CU (wave-capped).
// ---------------------------------------------------------------------------
__global__ __launch_bounds__(1024) void fsort_gather_kernel(
    const int* __restrict__ pool, const int* __restrict__ gcur,
    const unsigned short* __restrict__ g, const float* __restrict__ in_norm,
    const float* __restrict__ bias, float* __restrict__ out)
{
    __shared__ int pairs[CAPB];
    __shared__ int sorted_s[CAPB];
    __shared__ int fcnt[BSZ];
    __shared__ int s0[BSZ];
    __shared__ int sexcl[BSZ];
    __shared__ int wsum[4];
    __shared__ int woff[4];

    const int t = threadIdx.x, b = blockIdx.x;
    const int lane = t & 63, wv = t >> 6;

    if (t < BSZ) fcnt[t] = 0;
    int cnt = gcur[b];
    if (cnt > CAPB) cnt = CAPB;   // statistically unreachable
    const int beg = b * CAPB;
    __syncthreads();

    for (int i = t; i < cnt; i += 1024) pairs[i] = pool[beg + i];
    __syncthreads();
    for (int i = t; i < cnt; i += 1024) atomicAdd(&fcnt[pairs[i] >> 17], 1);
    __syncthreads();

    // inclusive scan of fcnt[256]: per-wave shuffle scan + 4-wide fixup
    if (t < BSZ) {
        int v = fcnt[t];
        int incl = v;
        #pragma unroll
        for (int off = 1; off < 64; off <<= 1) {
            int n = __shfl_up(incl, off);
            if (lane >= off) incl += n;
        }
        s0[t] = incl;
        if (lane == 63) wsum[wv] = incl;
    }
    __syncthreads();
    if (t < 64) {
        int v = (t < 4) ? wsum[t] : 0;
        int incl = v;
        #pragma unroll
        for (int off = 1; off < 4; off <<= 1) {
            int n = __shfl_up(incl, off);
            if (lane >= off) incl += n;
        }
        if (t < 4) woff[t] = incl - v;
    }
    __syncthreads();
    if (t < BSZ) {
        int sv = s0[t] + woff[t >> 6];
        s0[t] = sv;                 // local inclusive END per node
        sexcl[t] = sv - fcnt[t];    // local scatter cursor
    }
    __syncthreads();

    // counting-sort scatter into LDS
    for (int i = t; i < cnt; i += 1024) {
        int p = pairs[i];
        int pos = atomicAdd(&sexcl[p >> 17], 1);
        sorted_s[pos] = p & 0x1FFFF;
    }
    __syncthreads();

    // gather: wave wv owns local nodes [wv*16, wv*16+16)
    const unsigned* gp = (const unsigned*)g;
    const float2 bl = ((const float2*)bias)[lane];   // cols 2*lane, 2*lane+1
    const int node0 = b << 8;
    const int nEnd = wv * 16 + 16;
    for (int nl = wv * 16; nl < nEnd; ++nl) {
        const int node = node0 + nl;
        if (node >= N_NODES) break;
        const int start = (nl == 0) ? 0 : s0[nl - 1];
        const int end = s0[nl];
        float ax = 0.f, ay = 0.f;
        int e = start;
        for (; e + 7 < end; e += 8) {
            unsigned u0 = gp[(size_t)sorted_s[e]     * 64 + lane];
            unsigned u1 = gp[(size_t)sorted_s[e + 1] * 64 + lane];
            unsigned u2 = gp[(size_t)sorted_s[e + 2] * 64 + lane];
            unsigned u3 = gp[(size_t)sorted_s[e + 3] * 64 + lane];
            unsigned u4 = gp[(size_t)sorted_s[e + 4] * 64 + lane];
            unsigned u5 = gp[(size_t)sorted_s[e + 5] * 64 + lane];
            unsigned u6 = gp[(size_t)sorted_s[e + 6] * 64 + lane];
            unsigned u7 = gp[(size_t)sorted_s[e + 7] * 64 + lane];
            ax += __uint_as_float(u0 << 16) + __uint_as_float(u1 << 16)
                + __uint_as_float(u2 << 16) + __uint_as_float(u3 << 16)
                + __uint_as_float(u4 << 16) + __uint_as_float(u5 << 16)
                + __uint_as_float(u6 << 16) + __uint_as_float(u7 << 16);
            ay += __uint_as_float(u0 & 0xffff0000u) + __uint_as_float(u1 & 0xffff0000u)
                + __uint_as_float(u2 & 0xffff0000u) + __uint_as_float(u3 & 0xffff0000u)
                + __uint_as_float(u4 & 0xffff0000u) + __uint_as_float(u5 & 0xffff0000u)
                + __uint_as_float(u6 & 0xffff0000u) + __uint_as_float(u7 & 0xffff0000u);
        }
        for (; e + 3 < end; e += 4) {
            unsigned u0 = gp[(size_t)sorted_s[e]     * 64 + lane];
            unsigned u1 = gp[(size_t)sorted_s[e + 1] * 64 + lane];
            unsigned u2 = gp[(size_t)sorted_s[e + 2] * 64 + lane];
            unsigned u3 = gp[(size_t)sorted_s[e + 3] * 64 + lane];
            ax += __uint_as_float(u0 << 16) + __uint_as_float(u1 << 16)
                + __uint_as_float(u2 << 16) + __uint_as_float(u3 << 16);
            ay += __uint_as_float(u0 & 0xffff0000u) + __uint_as_float(u1 & 0xffff0000u)
                + __uint_as_float(u2 & 0xffff0000u) + __uint_as_float(u3 & 0xffff0000u);
        }
        for (; e < end; ++e) {
            unsigned u = gp[(size_t)sorted_s[e] * 64 + lane];
            ax += __uint_as_float(u << 16);
            ay += __uint_as_float(u & 0xffff0000u);
        }
        const float rin = 1.0f / in_norm[node];
        float2 o; o.x = ax * rin + bl.x; o.y = ay * rin + bl.y;
        ((float2*)out)[(size_t)node * 64 + lane] = o;
    }
}

// ---------------------------------------------------------------------------
// Parachute fallback (tiny ws): R1 atomic scatter + fp32 VALU transform.
// ---------------------------------------------------------------------------
__global__ __launch_bounds__(256) void scatter_kernel(
    const float* __restrict__ feat, const float* __restrict__ out_norm,
    const int* __restrict__ src, const int* __restrict__ dst,
    float* __restrict__ agg)
{
    const int wave = threadIdx.x >> 6;
    const int lane = threadIdx.x & 63;
    const int e = blockIdx.x * 4 + wave;
    const int s = src[e];
    const int d = dst[e];
    const float rn = 1.0f / out_norm[s];
    const float2 v = ((const float2*)(feat + (size_t)s * F))[lane];
    float* ap = agg + (size_t)d * F + lane * 2;
    unsafeAtomicAdd(ap,     v.x * rn);
    unsafeAtomicAdd(ap + 1, v.y * rn);
}

__global__ __launch_bounds__(256) void transform_kernel(
    float* __restrict__ out, const float* __restrict__ in_norm,
    const float* __restrict__ W, const float* __restrict__ bias)
{
    __shared__ float Wt[F * F];
    const int t = threadIdx.x;
    #pragma unroll
    for (int i = 0; i < (F * F) / 256; ++i) {
        int idx = t + i * 256;
        int j = idx >> 7;
        int k = idx & (F - 1);
        Wt[k * F + j] = W[idx];
    }
    __syncthreads();
    const int wave = t >> 6, lane = t & 63;
    const float b0 = bias[lane];
    const float b1 = bias[lane + 64];
    const int ngroups = N_NODES / 16;
    for (int gi = blockIdx.x; gi < ngroups; gi += gridDim.x) {
        const int r = gi * 16 + wave * 4;
        const float4* a0 = (const float4*)(out + (size_t)r * F);
        const float4* a1 = a0 + F / 4;
        const float4* a2 = a0 + 2 * (F / 4);
        const float4* a3 = a0 + 3 * (F / 4);
        float acc00 = 0.f, acc01 = 0.f, acc10 = 0.f, acc11 = 0.f;
        float acc20 = 0.f, acc21 = 0.f, acc30 = 0.f, acc31 = 0.f;
        for (int k4 = 0; k4 < F / 4; ++k4) {
            const float4 x0 = a0[k4]; const float4 x1 = a1[k4];
            const float4 x2 = a2[k4]; const float4 x3 = a3[k4];
            const float xs0[4] = {x0.x, x0.y, x0.z, x0.w};
            const float xs1[4] = {x1.x, x1.y, x1.z, x1.w};
            const float xs2[4] = {x2.x, x2.y, x2.z, x2.w};
            const float xs3[4] = {x3.x, x3.y, x3.z, x3.w};
            #pragma unroll
            for (int kk = 0; kk < 4; ++kk) {
                const int k = k4 * 4 + kk;
                const float w0 = Wt[k * F + lane];
                const float w1 = Wt[k * F + 64 + lane];
                acc00 = fmaf(xs0[kk], w0, acc00); acc01 = fmaf(xs0[kk], w1, acc01);
                acc10 = fmaf(xs1[kk], w0, acc10); acc11 = fmaf(xs1[kk], w1, acc11);
                acc20 = fmaf(xs2[kk], w0, acc20); acc21 = fmaf(xs2[kk], w1, acc21);
                acc30 = fmaf(xs3[kk], w0, acc30); acc31 = fmaf(xs3[kk], w1, acc31);
            }
        }
        const float i0 = 1.0f / in_norm[r + 0];
        const float i1 = 1.0f / in_norm[r + 1];
        const float i2 = 1.0f / in_norm[r + 2];
        const float i3 = 1.0f / in_norm[r + 3];
        out[(size_t)(r + 0) * F + lane]      = acc00 * i0 + b0;
        out[(size_t)(r + 0) * F + 64 + lane] = acc01 * i0 + b1;
        out[(size_t)(r + 1) * F + lane]      = acc10 * i1 + b0;
        out[(size_t)(r + 1) * F + 64 + lane] = acc11 * i1 + b1;
        out[(size_t)(r + 2) * F + lane]      = acc20 * i2 + b0;
        out[(size_t)(r + 2) * F + 64 + lane] = acc21 * i2 + b1;
        out[(size_t)(r + 3) * F + lane]      = acc30 * i3 + b0;
        out[(size_t)(r + 3) * F + 64 + lane] = acc31 * i3 + b1;
    }
}

extern "C" void kernel_launch(void* const* d_in, const int* in_sizes, int n_in,
                              void* d_out, int out_size, void* d_ws, size_t ws_size,
                              hipStream_t stream) {
    const float* feat     = (const float*)d_in[0];
    const float* in_norm  = (const float*)d_in[1];
    const float* out_norm = (const float*)d_in[2];
    const int*   src      = (const int*)d_in[3];
    const int*   dst      = (const int*)d_in[4];
    const float* W        = (const float*)d_in[5];
    const float* b        = (const float*)d_in[6];
    float* out = (float*)d_out;

    if (ws_size >= (size_t)WS_V9) {
        char* w = (char*)d_ws;
        int*            pool = (int*)(w + 0);
        int*            gcur = (int*)(w + 7156864);
        unsigned short* g    = (unsigned short*)(w + 7160960);

        hipMemsetAsync(gcur, 0, 4096, stream);
        front_kernel<<<FRONT_NBLK, 512, 0, stream>>>(
            feat, out_norm, src, dst, W, g, pool, gcur);
        fsort_gather_kernel<<<NB2, 1024, 0, stream>>>(
            pool, gcur, g, in_norm, b, out);
    } else {
        hipMemsetAsync(out, 0, (size_t)N_NODES * F * sizeof(float), stream);
        scatter_kernel<<<N_EDGES / 4, 256, 0, stream>>>(feat, out_norm, src, dst, out);
        transform_kernel<<<2048, 256, 0, stream>>>(out, in_norm, W, b);
    }
}